// Round 3
// baseline (909.825 us; speedup 1.0000x reference)
//
#include <hip/hip_runtime.h>

#define NB 512
#define NT 256
#define NI 32
#define NH 128
#define NG 512

#define L2E  1.4426950408889634f
#define L2E2 2.8853900817779268f

typedef __attribute__((ext_vector_type(8))) short bf16x8;
typedef __attribute__((ext_vector_type(4))) float f32x4;

__device__ __forceinline__ unsigned short f2bf_rne(float f) {
    unsigned u = __float_as_uint(f);
    return (unsigned short)((u + 0x7FFFu + ((u >> 16) & 1u)) >> 16);
}
__device__ __forceinline__ void split2(float a, float b, unsigned& hi, unsigned& lo) {
    unsigned short ha = f2bf_rne(a), hb = f2bf_rne(b);
    float ra = a - __uint_as_float((unsigned)ha << 16);
    float rb = b - __uint_as_float((unsigned)hb << 16);
    hi = (unsigned)ha | ((unsigned)hb << 16);
    lo = (unsigned)f2bf_rne(ra) | ((unsigned)f2bf_rne(rb) << 16);
}
__device__ __forceinline__ bf16x8 u4bf(uint4 u) {
    union { uint4 u; bf16x8 v; } c; c.u = u; return c.v;
}
#define MFMA16(accv, av, bv) \
    accv = __builtin_amdgcn_mfma_f32_16x16x32_bf16(av, bv, accv, 0, 0, 0)

// LDS-only barrier: orders ds ops across waves WITHOUT draining vmcnt.
__device__ __forceinline__ void lds_barrier() {
    asm volatile("s_waitcnt lgkmcnt(0)\n\ts_barrier" ::: "memory");
}

// ---------------------------------------------------------------------------
// Paired MFMA LSTM recurrence: 64 blocks x 512 threads.
//   role 0 (blk  0-31): layer-0 recurrence, chunk i, x-GEMM FUSED (R17)
//   role 1 (blk 32-63): layer-1 recurrence, chunk i-1 (reads negated-scaled xg1)
// R17 (budget: MFMA 466 + VALU 670 + trans 640 cyc/SIMD/step, rest stall):
//  - role0 computes x.W_ih0 in-kernel: +12 MFMA/wave/step (K=32 split-bf16),
//    W_ih0 frags staged scaled in LDS (dense b128, conflict-free). Kills all
//    gemm<1> dispatches and role0's 16 xg loads/step.
//  - exp2-folding: W_hh/W_ih/bias pre-scaled by log2e (2log2e for g-gate);
//    gemm epilogue emits NEGATED-scaled xg1 -> e = v_exp(m), no mul, and
//    fused rcp forms: sig(i)*tanh(g) = (1-eg)*rcp((1+ei)(1+eg)). 10->8
//    trans/r, fewer muls. State h/c stay in real units.
//  - accP/accQ split per gate: MFMA dep chain 12 -> ~6-8.
// ---------------------------------------------------------------------------
__global__ __launch_bounds__(512, 2)
void recur_pair(const float* __restrict__ x,
                const float* __restrict__ xg1,   // negated-scaled, rows b*Tc+tl
                const float* __restrict__ w_hh0,
                const float* __restrict__ w_hh1,
                const float* __restrict__ w_ih0,
                const float* __restrict__ b_ih0, const float* __restrict__ b_hh0,
                float* __restrict__ h0buf,
                float* __restrict__ h0s, float* __restrict__ c0s,
                float* __restrict__ h1s, float* __restrict__ c1s,
                int Tc, int doA, int doB, int firstA, int firstB, int t0A)
{
    __shared__ __align__(16) unsigned short Hh[2][16][128];   // 8192 B
    __shared__ __align__(16) unsigned short Hl[2][16][128];   // 8192 B
    __shared__ __align__(16) uint4 WIh[32][64];               // 32768 B
    __shared__ __align__(16) uint4 WIl[32][64];               // 32768 B

    const int role = blockIdx.x >> 5;
    if (role == 0 && !doA) return;
    if (role == 1 && !doB) return;

    const float* wsrc  = role ? w_hh1 : w_hh0;
    float*       hs    = role ? h1s : h0s;
    float*       cs    = role ? c1s : c0s;
    const int    first = role ? firstB : firstA;

    const int p    = blockIdx.x & 31;
    const int tid  = threadIdx.x;
    const int wv   = tid >> 6;
    const int lane = tid & 63;
    const int quad = lane >> 4;
    const int ml   = lane & 15;
    const int j    = 16 * wv + ml;

    // ---- stage W_hh (scaled by per-gate log2e factor): hi+lo in registers ----
    bf16x8 wh[4][4], wl[4][4];
#pragma unroll
    for (int t = 0; t < 4; ++t) {
        const float sc = (t == 2) ? L2E2 : L2E;
#pragma unroll
        for (int q = 0; q < 4; ++q) {
            int n = (t * 8 + wv) * 16 + ml;
            const float* s = wsrc + (size_t)n * NH + q * 32 + quad * 8;
            float4 v0 = *(const float4*)s;
            float4 v1 = *(const float4*)(s + 4);
            uint4 H, L;
            split2(v0.x * sc, v0.y * sc, H.x, L.x); split2(v0.z * sc, v0.w * sc, H.y, L.y);
            split2(v1.x * sc, v1.y * sc, H.z, L.z); split2(v1.z * sc, v1.w * sc, H.w, L.w);
            wh[t][q] = u4bf(H);
            wl[t][q] = u4bf(L);
        }
    }

    // ---- precomputed per-thread offsets ----
    int ro[4];
#pragma unroll
    for (int q = 0; q < 4; ++q)
        ro[q] = ((ml * 256 + q * 64 + quad * 16) ^ ((ml & 7) << 4));
    int wo[4];
    size_t hb_r[4], sb_r[4];
#pragma unroll
    for (int r = 0; r < 4; ++r) {
        int m = quad * 4 + r;
        wo[r]   = ((m * 256 + j * 2) ^ ((m & 7) << 4));
        hb_r[r] = (size_t)(p * 16 + m) * Tc * NH + j;
        sb_r[r] = (size_t)(p * 16 + m) * NH + j;
    }

    // ---- initial c/h ----
    float cr[4];
#pragma unroll
    for (int r = 0; r < 4; ++r) {
        float h = 0.f, c = 0.f;
        if (!first) {
            h = hs[sb_r[r]];
            c = cs[sb_r[r]];
        }
        cr[r] = c;
        unsigned short hi = f2bf_rne(h);
        float res = h - __uint_as_float((unsigned)hi << 16);
        unsigned short lo = f2bf_rne(res);
        *(unsigned short*)((char*)&Hh[0][0][0] + wo[r]) = hi;
        *(unsigned short*)((char*)&Hl[0][0][0] + wo[r]) = lo;
    }

    // fused activation: inputs are m_g = -(scaled preact); returns h, updates c.
    auto activ = [&](float mi, float mf, float mg, float mo, float& c)
        __attribute__((always_inline)) -> float {
        float ei = exp2f(mi), ef = exp2f(mf), eg = exp2f(mg), eo = exp2f(mo);
        float rf  = __builtin_amdgcn_rcpf(1.0f + ef);
        float rig = __builtin_amdgcn_rcpf((1.0f + ei) * (1.0f + eg));
        float cn  = c * rf + (1.0f - eg) * rig;
        c = cn;
        float ec = exp2f(cn * -L2E2);
        float rh = __builtin_amdgcn_rcpf((1.0f + eo) * (1.0f + ec));
        return (1.0f - ec) * rh;
    };

    if (role == 0) {
        // ---- stage W_ih0 frags (scaled) into LDS ----
#pragma unroll
        for (int t = 0; t < 4; ++t) {
            const float sc = (t == 2) ? L2E2 : L2E;
            int n = (t * 8 + wv) * 16 + ml;
            const float* s = w_ih0 + (size_t)n * NI + quad * 8;
            float4 v0 = *(const float4*)s;
            float4 v1 = *(const float4*)(s + 4);
            uint4 H, L;
            split2(v0.x * sc, v0.y * sc, H.x, L.x); split2(v0.z * sc, v0.w * sc, H.y, L.y);
            split2(v1.x * sc, v1.y * sc, H.z, L.z); split2(v1.z * sc, v1.w * sc, H.w, L.w);
            WIh[t * 8 + wv][lane] = H;
            WIl[t * 8 + wv][lane] = L;
        }
        // negated scaled bias
        float nb[4];
#pragma unroll
        for (int t = 0; t < 4; ++t) {
            const float sc = (t == 2) ? L2E2 : L2E;
            int n = t * 128 + j;
            nb[t] = -(b_ih0[n] + b_hh0[n]) * sc;
        }
        __syncthreads();

        const float* xrow = x + (size_t)(p * 16 + ml) * NT * NI + quad * 8;
        auto xload = [&](float4& a, float4& b, int TL) __attribute__((always_inline)) {
            int tc_ = TL < Tc ? TL : Tc - 1;
            const float* sp = xrow + (size_t)(t0A + tc_) * NI;
            a = *(const float4*)sp;
            b = *(const float4*)(sp + 4);
        };

        auto step0 = [&](int TL, int BUF, float4 x0, float4 x1)
            __attribute__((always_inline)) {
            const char* hb = (const char*)&Hh[BUF][0][0];
            const char* lb = (const char*)&Hl[BUF][0][0];
            char* hbn = (char*)&Hh[BUF ^ 1][0][0];
            char* lbn = (char*)&Hl[BUF ^ 1][0][0];

            uint4 XH, XL;
            split2(x0.x, x0.y, XH.x, XL.x); split2(x0.z, x0.w, XH.y, XL.y);
            split2(x1.x, x1.y, XH.z, XL.z); split2(x1.z, x1.w, XH.w, XL.w);
            bf16x8 xh = u4bf(XH), xl = u4bf(XL);

            f32x4 P[4] = {}, Q[4] = {};
            // x-part first (no LDS dependency): fills while h frags arrive
#pragma unroll
            for (int t = 0; t < 4; ++t) {
                bf16x8 wihh = u4bf(WIh[t * 8 + wv][lane]);
                bf16x8 wihl = u4bf(WIl[t * 8 + wv][lane]);
                MFMA16(P[t], xh, wihh);
                MFMA16(Q[t], xl, wihh);
                MFMA16(Q[t], xh, wihl);
            }
#pragma unroll
            for (int q = 0; q < 4; ++q) {
                bf16x8 ah = *(const bf16x8*)(hb + ro[q]);
                bf16x8 al = *(const bf16x8*)(lb + ro[q]);
#pragma unroll
                for (int t = 0; t < 4; ++t) {
                    MFMA16(P[t], ah, wh[t][q]);
                    MFMA16(Q[t], al, wh[t][q]);
                    if (q & 1) { MFMA16(P[t], ah, wl[t][q]); }
                    else       { MFMA16(Q[t], ah, wl[t][q]); }
                }
            }
#pragma unroll
            for (int r = 0; r < 4; ++r) {
                float mi = nb[0] - P[0][r] - Q[0][r];
                float mf = nb[1] - P[1][r] - Q[1][r];
                float mg = nb[2] - P[2][r] - Q[2][r];
                float mo = nb[3] - P[3][r] - Q[3][r];
                float hn = activ(mi, mf, mg, mo, cr[r]);
                unsigned short hi = f2bf_rne(hn);
                float res = hn - __uint_as_float((unsigned)hi << 16);
                unsigned short lo = f2bf_rne(res);
                *(unsigned short*)(hbn + wo[r]) = hi;
                *(unsigned short*)(lbn + wo[r]) = lo;
                h0buf[hb_r[r] + (size_t)TL * NH] = hn;
                if (TL == Tc - 1) {
                    hs[sb_r[r]] = hn;
                    cs[sb_r[r]] = cr[r];
                }
            }
        };

        float4 xa0, xa1, xb0, xb1;
        xload(xa0, xa1, 0);
        for (int tl = 0; tl < Tc; tl += 2) {
            xload(xb0, xb1, tl + 1);
            step0(tl, 0, xa0, xa1);
            lds_barrier();
            xload(xa0, xa1, tl + 2);
            step0(tl + 1, 1, xb0, xb1);
            lds_barrier();
        }
    } else {
        __syncthreads();

        const size_t rs = (size_t)Tc * NG;
        const size_t rowb0 = ((size_t)(p * 16 + quad * 4) * Tc) * NG + j;

        auto prefetch = [&](float (&dst)[4][4], int tlx) __attribute__((always_inline)) {
            int tc_ = tlx < Tc ? tlx : Tc - 1;
            const size_t rowb = rowb0 + (size_t)tc_ * NG;
#pragma unroll
            for (int t = 0; t < 4; ++t)
#pragma unroll
                for (int r = 0; r < 4; ++r)
                    dst[t][r] = xg1[rowb + (size_t)r * rs + t * 128];
        };

        auto step1 = [&](int TL, int BUF, const float (&xgv)[4][4])
            __attribute__((always_inline)) {
            const char* hb = (const char*)&Hh[BUF][0][0];
            const char* lb = (const char*)&Hl[BUF][0][0];
            char* hbn = (char*)&Hh[BUF ^ 1][0][0];
            char* lbn = (char*)&Hl[BUF ^ 1][0][0];

            f32x4 P[4] = {}, Q[4] = {};
#pragma unroll
            for (int q = 0; q < 4; ++q) {
                bf16x8 ah = *(const bf16x8*)(hb + ro[q]);
                bf16x8 al = *(const bf16x8*)(lb + ro[q]);
#pragma unroll
                for (int t = 0; t < 4; ++t) {
                    MFMA16(P[t], ah, wh[t][q]);
                    MFMA16(Q[t], al, wh[t][q]);
                    if (q & 1) { MFMA16(P[t], ah, wl[t][q]); }
                    else       { MFMA16(Q[t], ah, wl[t][q]); }
                }
            }
#pragma unroll
            for (int r = 0; r < 4; ++r) {
                float mi = xgv[0][r] - P[0][r] - Q[0][r];
                float mf = xgv[1][r] - P[1][r] - Q[1][r];
                float mg = xgv[2][r] - P[2][r] - Q[2][r];
                float mo = xgv[3][r] - P[3][r] - Q[3][r];
                float hn = activ(mi, mf, mg, mo, cr[r]);
                unsigned short hi = f2bf_rne(hn);
                float res = hn - __uint_as_float((unsigned)hi << 16);
                unsigned short lo = f2bf_rne(res);
                *(unsigned short*)(hbn + wo[r]) = hi;
                *(unsigned short*)(lbn + wo[r]) = lo;
                if (TL == Tc - 1) {
                    hs[sb_r[r]] = hn;
                    cs[sb_r[r]] = cr[r];
                }
            }
        };

        float xga[4][4], xgb[4][4];
        prefetch(xga, 0);
        for (int tl = 0; tl < Tc; tl += 2) {
            prefetch(xgb, tl + 1);
            step1(tl, 0, xga);
            lds_barrier();
            prefetch(xga, tl + 2);
            step1(tl + 1, 1, xgb);
            lds_barrier();
        }
    }
}

// ---------------------------------------------------------------------------
// Split-bf16 MFMA GEMM: C = -( A @ Bw^T + (bi+bh) ) * s_gate  (negated-scaled
// xg1 for the recurrence's exp2-folded gates). K=128, A rows = b*Tc+tl.
// ---------------------------------------------------------------------------
__global__ __launch_bounds__(256)
void gemm_ih1(const float* __restrict__ A,
              const float* __restrict__ Bw,
              const float* __restrict__ bi, const float* __restrict__ bh,
              float* __restrict__ C)
{
    constexpr int K = 128;
    __shared__ __align__(16) unsigned short Ah[4][128][8], Al[4][128][8];
    __shared__ __align__(16) unsigned short Bh[4][64][8],  Bl[4][64][8];
    const int tid  = threadIdx.x;
    const int n0   = blockIdx.x * 64;
    const int m0   = blockIdx.y * 128;
    const int wv   = tid >> 6;
    const int lane = tid & 63;
    const int quad = lane >> 4, ml = lane & 15;

    const float s = ((blockIdx.x >> 1) == 2) ? L2E2 : L2E;   // g-gate columns
    f32x4 acc[2][4] = {};
    float nbs[4];
#pragma unroll
    for (int nt = 0; nt < 4; ++nt) {
        int n = n0 + nt * 16 + ml;
        nbs[nt] = -(bi[n] + bh[n]) * s;
    }

    for (int kp = 0; kp < 4; ++kp) {
        if (kp) __syncthreads();
#pragma unroll
        for (int r = 0; r < 2; ++r) {
            int u = tid + 256 * r;
            int m = u >> 2, ck = u & 3;
            const float* sp = A + (size_t)(m0 + m) * K + kp * 32 + ck * 8;
            float4 v0 = *(const float4*)sp;
            float4 v1 = *(const float4*)(sp + 4);
            uint4 H, L;
            split2(v0.x, v0.y, H.x, L.x); split2(v0.z, v0.w, H.y, L.y);
            split2(v1.x, v1.y, H.z, L.z); split2(v1.z, v1.w, H.w, L.w);
            *(uint4*)&Ah[ck][m][0] = H;
            *(uint4*)&Al[ck][m][0] = L;
        }
        {
            int n = tid >> 2, ck = tid & 3;
            const float* sp = Bw + (size_t)(n0 + n) * K + kp * 32 + ck * 8;
            float4 v0 = *(const float4*)sp;
            float4 v1 = *(const float4*)(sp + 4);
            uint4 H, L;
            split2(v0.x, v0.y, H.x, L.x); split2(v0.z, v0.w, H.y, L.y);
            split2(v1.x, v1.y, H.z, L.z); split2(v1.z, v1.w, H.w, L.w);
            *(uint4*)&Bh[ck][n][0] = H;
            *(uint4*)&Bl[ck][n][0] = L;
        }
        __syncthreads();

        bf16x8 ah0 = *(const bf16x8*)&Ah[quad][(2 * wv + 0) * 16 + ml][0];
        bf16x8 al0 = *(const bf16x8*)&Al[quad][(2 * wv + 0) * 16 + ml][0];
        bf16x8 ah1 = *(const bf16x8*)&Ah[quad][(2 * wv + 1) * 16 + ml][0];
        bf16x8 al1 = *(const bf16x8*)&Al[quad][(2 * wv + 1) * 16 + ml][0];
#pragma unroll
        for (int nt = 0; nt < 4; ++nt) {
            bf16x8 bhv = *(const bf16x8*)&Bh[quad][nt * 16 + ml][0];
            bf16x8 blv = *(const bf16x8*)&Bl[quad][nt * 16 + ml][0];
            MFMA16(acc[0][nt], ah0, bhv);
            MFMA16(acc[0][nt], ah0, blv);
            MFMA16(acc[0][nt], al0, bhv);
            MFMA16(acc[1][nt], ah1, bhv);
            MFMA16(acc[1][nt], ah1, blv);
            MFMA16(acc[1][nt], al1, bhv);
        }
    }

#pragma unroll
    for (int mt = 0; mt < 2; ++mt)
#pragma unroll
        for (int nt = 0; nt < 4; ++nt)
#pragma unroll
            for (int reg = 0; reg < 4; ++reg) {
                int m = m0 + (2 * wv + mt) * 16 + quad * 4 + reg;
                int n = n0 + nt * 16 + ml;
                C[(size_t)m * NG + n] = fmaf(acc[mt][nt][reg], -s, nbs[nt]);
            }
}

// ---------------------------------------------------------------------------
// out[b] = fc2_w . relu(fc1_w @ h1_last[b] + fc1_b) + fc2_b
// ---------------------------------------------------------------------------
__global__ void fc_head(const float* __restrict__ h1,
                        const float* __restrict__ fc1w, const float* __restrict__ fc1b,
                        const float* __restrict__ fc2w, const float* __restrict__ fc2b,
                        float* __restrict__ out)
{
    int b = blockIdx.x, j = threadIdx.x;
    const float4* wr = (const float4*)(fc1w + (size_t)j * NH);
    const float4* hv = (const float4*)(h1 + (size_t)b * NH);
    float acc = fc1b[j];
#pragma unroll
    for (int q = 0; q < 32; ++q) {
        float4 w = wr[q], h = hv[q];
        acc += w.x * h.x + w.y * h.y + w.z * h.z + w.w * h.w;
    }
    float z = fmaxf(acc, 0.0f);
    float p = fc2w[j] * z;
#pragma unroll
    for (int off = 32; off > 0; off >>= 1) p += __shfl_down(p, off);
    if (j == 0) out[b] = p + fc2b[0];
}

extern "C" void kernel_launch(void* const* d_in, const int* in_sizes, int n_in,
                              void* d_out, int out_size, void* d_ws, size_t ws_size,
                              hipStream_t stream)
{
    const float* x     = (const float*)d_in[0];
    const float* w_ih0 = (const float*)d_in[1];
    const float* w_hh0 = (const float*)d_in[2];
    const float* b_ih0 = (const float*)d_in[3];
    const float* b_hh0 = (const float*)d_in[4];
    const float* w_ih1 = (const float*)d_in[5];
    const float* w_hh1 = (const float*)d_in[6];
    const float* b_ih1 = (const float*)d_in[7];
    const float* b_hh1 = (const float*)d_in[8];
    const float* fc1w  = (const float*)d_in[9];
    const float* fc1b  = (const float*)d_in[10];
    const float* fc2w  = (const float*)d_in[11];
    const float* fc2b  = (const float*)d_in[12];
    float* out = (float*)d_out;
    float* ws  = (float*)d_ws;

    // Tc=32: pipeline wall-time = (NT + Tc) step-times; smaller chunk = less
    // fill/drain waste. ws need: xg1 + h0 + 4 state arrays (~43 MB @ Tc=32).
    int Tc = 32;
    while (Tc > 1 &&
           4ull * ((size_t)NB * Tc * (NG + NH) + 4ull * NB * NH) > ws_size)
        Tc >>= 1;

    size_t o_xg1 = 0;
    size_t o_h0  = o_xg1 + (size_t)NB * Tc * NG;
    size_t o_h0s = o_h0  + (size_t)NB * Tc * NH;
    size_t o_c0s = o_h0s + (size_t)NB * NH;
    size_t o_h1s = o_c0s + (size_t)NB * NH;
    size_t o_c1s = o_h1s + (size_t)NB * NH;

    const int nchunk = NT / Tc;

    for (int i = 0; i <= nchunk; ++i) {
        int doA = (i < nchunk), doB = (i >= 1);
        recur_pair<<<64, 512, 0, stream>>>(
            x, ws + o_xg1, w_hh0, w_hh1, w_ih0, b_ih0, b_hh0,
            ws + o_h0, ws + o_h0s, ws + o_c0s, ws + o_h1s, ws + o_c1s,
            Tc, doA, doB, i == 0, i == 1, i * Tc);
        if (i < nchunk)        // xg1 for chunk i (consumed by role1 next iter)
            gemm_ih1<<<dim3(8, NB * Tc / 128), 256, 0, stream>>>(
                ws + o_h0, w_ih1, b_ih1, b_hh1, ws + o_xg1);
    }
    fc_head<<<NB, 64, 0, stream>>>(ws + o_h1s, fc1w, fc1b, fc2w, fc2b, out);
}